// Round 5
// baseline (232.896 us; speedup 1.0000x reference)
//
#include <hip/hip_runtime.h>
#include <hip/hip_bf16.h>

// MultiHeadedAttention fused pipeline for MI355X (gfx950), bf16 MFMA path.
// R5 = R4 re-audited + attn blocks widened to 4 waves (staging amortization):
// - attn: swapped-QK^T 32x32 MFMA structure (lane-local softmax, register P
//   exchange, transposed O accumulation, XOR-swizzled K/V LDS), 256 thr/block.
// - proj_qkv z=2 epilogue LDS-transposed (was 2B-scatter at 4KB stride).
// - proj_o 64x64 tiles (512 blocks). Q pre-scaled by 0.125*log2e.

#define DEVI __device__ __forceinline__

typedef float f32x4 __attribute__((ext_vector_type(4)));
typedef float f32x16 __attribute__((ext_vector_type(16)));
typedef __bf16 bf16x8 __attribute__((ext_vector_type(8)));

constexpr int S  = 2048;
constexpr int D  = 512;
constexpr int H  = 8;
constexpr int DK = 64;
constexpr int BATCH = 2;
constexpr int BS = BATCH * S;  // 4096

constexpr float SCALE_QK = 0.18033688011112433f;  // 0.125 * log2(e)
constexpr float EPS2     = 1.4426950408889634e9f; // 1e9 * log2(e)

DEVI unsigned short f2bf(float f) {
  union { float f; unsigned u; } v; v.f = f;
  unsigned r = v.u + 0x7fffu + ((v.u >> 16) & 1u);  // round-to-nearest-even
  return (unsigned short)(r >> 16);
}

DEVI unsigned pk2(float a, float b) {
  return (unsigned)f2bf(a) | ((unsigned)f2bf(b) << 16);
}

DEVI f32x4 mfma16(bf16x8 a, bf16x8 b, f32x4 c) {
  return __builtin_amdgcn_mfma_f32_16x16x32_bf16(a, b, c, 0, 0, 0);
}
DEVI f32x16 mfma32(bf16x8 a, bf16x8 b, f32x16 c) {
  return __builtin_amdgcn_mfma_f32_32x32x16_bf16(a, b, c, 0, 0, 0);
}

DEVI bf16x8 ldg8(const unsigned short* p) { return *(const bf16x8*)p; }

// -------------------------------------------------------------- prep_w ----
// Wt [4][512][512] bf16 stored [n][d] (B^T layout), via 64x64 LDS transpose.
__global__ __launch_bounds__(256) void prep_w_kernel(
    const float* __restrict__ Wq, const float* __restrict__ Wk,
    const float* __restrict__ Wv, const float* __restrict__ Wo,
    unsigned short* __restrict__ Wt)
{
  __shared__ float T[64][65];
  int bid = blockIdx.x;
  int g = bid >> 6, t = bid & 63;
  int tn = t >> 3, td = t & 7;
  int n0 = tn * 64, d0 = td * 64;
  int tid = threadIdx.x;
  const float* src = (g == 0) ? Wq : (g == 1) ? Wk : (g == 2) ? Wv : Wo;

  #pragma unroll
  for (int cc = 0; cc < 4; ++cc) {
    int id = tid + cc * 256;
    int dd = id >> 4, f4 = (id & 15) * 4;
    const float* p = (g < 3)
      ? src + ((size_t)tn * D + d0 + dd) * DK + f4
      : src + (size_t)(d0 + dd) * D + n0 + f4;
    float4 x = *(const float4*)p;
    T[dd][f4 + 0] = x.x; T[dd][f4 + 1] = x.y;
    T[dd][f4 + 2] = x.z; T[dd][f4 + 3] = x.w;
  }
  __syncthreads();

  #pragma unroll
  for (int cc = 0; cc < 2; ++cc) {
    int id = tid + cc * 256;
    int nn = id >> 3, ch = (id & 7) * 8;
    unsigned short o8[8];
    #pragma unroll
    for (int j = 0; j < 8; ++j) o8[j] = f2bf(T[ch + j][nn]);
    *(uint4*)&Wt[((size_t)g * D + n0 + nn) * D + d0 + ch] = *(const uint4*)o8;
  }
}

// ------------------------------------------------------------- QKV GEMM ----
// z=0 -> Qb (pre-scaled by SCALE_QK); z=1 -> Kb; z=2 -> Vtb [b][h][dk][s]
// via LDS-transposed coalesced epilogue.
__global__ __launch_bounds__(256) void proj_qkv_kernel(
    const float* __restrict__ query, const float* __restrict__ key,
    const float* __restrict__ value, const unsigned short* __restrict__ Wt,
    const float* __restrict__ bq, const float* __restrict__ bk, const float* __restrict__ bv,
    unsigned short* __restrict__ Qb, unsigned short* __restrict__ Kb,
    unsigned short* __restrict__ Vtb)
{
  int z = blockIdx.z;
  const float* A = (z == 0) ? query : (z == 1) ? key : value;
  const unsigned short* Bt = Wt + (size_t)z * D * D;
  const float* bias = (z == 0) ? bq : (z == 1) ? bk : bv;

  __shared__ __align__(16) unsigned short SM[2 * 128 * 72];
  unsigned short (*At)[72]    = (unsigned short(*)[72])SM;
  unsigned short (*Btile)[72] = (unsigned short(*)[72])(SM + 128 * 72);

  int tid = threadIdx.x;
  int w = tid >> 6, l = tid & 63;
  int g = l >> 4, c = l & 15;
  int wm = w >> 1, wn = w & 1;
  int m0 = blockIdx.y * 128, n0 = blockIdx.x * 128;

  f32x4 acc[4][4];
  #pragma unroll
  for (int i = 0; i < 4; ++i)
    #pragma unroll
    for (int j = 0; j < 4; ++j) acc[i][j] = f32x4{0.f, 0.f, 0.f, 0.f};

  for (int k0 = 0; k0 < D; k0 += 64) {
    __syncthreads();
    #pragma unroll
    for (int cc = 0; cc < 4; ++cc) {
      int id = tid + cc * 256;
      int row = id >> 3, ch = (id & 7) * 8;
      const float* p = A + (size_t)(m0 + row) * D + k0 + ch;
      float4 x0 = *(const float4*)p, x1 = *(const float4*)(p + 4);
      unsigned short o8[8] = { f2bf(x0.x), f2bf(x0.y), f2bf(x0.z), f2bf(x0.w),
                               f2bf(x1.x), f2bf(x1.y), f2bf(x1.z), f2bf(x1.w) };
      *(uint4*)&At[row][ch] = *(const uint4*)o8;
      *(bf16x8*)&Btile[row][ch] = ldg8(Bt + (size_t)(n0 + row) * D + k0 + ch);
    }
    __syncthreads();
    #pragma unroll
    for (int dc = 0; dc < 2; ++dc) {
      bf16x8 af[4], bv4[4];
      #pragma unroll
      for (int i = 0; i < 4; ++i)
        af[i] = *(const bf16x8*)&At[wm * 64 + i * 16 + c][dc * 32 + 8 * g];
      #pragma unroll
      for (int j = 0; j < 4; ++j)
        bv4[j] = *(const bf16x8*)&Btile[wn * 64 + j * 16 + c][dc * 32 + 8 * g];
      #pragma unroll
      for (int i = 0; i < 4; ++i)
        #pragma unroll
        for (int j = 0; j < 4; ++j)
          acc[i][j] = mfma16(af[i], bv4[j], acc[i][j]);
    }
  }

  if (z < 2) {
    #pragma unroll
    for (int i = 0; i < 4; ++i) {
      #pragma unroll
      for (int j = 0; j < 4; ++j) {
        int col = n0 + wn * 64 + j * 16 + c;
        float bb = bias[col];
        #pragma unroll
        for (int r = 0; r < 4; ++r) {
          int m = m0 + wm * 64 + i * 16 + 4 * g + r;
          float vv = acc[i][j][r] + bb;
          if (z == 0) vv *= SCALE_QK;
          unsigned short o = f2bf(vv);
          if (z == 0) Qb[(size_t)m * D + col] = o;
          else        Kb[(size_t)m * D + col] = o;
        }
      }
    }
  } else {
    // LDS-transposed epilogue for Vtb [b][h*64+dk][s].
    __syncthreads();
    unsigned short (*Vl)[130] = (unsigned short(*)[130])SM;   // 128*130 <= 2*128*72
    #pragma unroll
    for (int i = 0; i < 4; ++i)
      #pragma unroll
      for (int j = 0; j < 4; ++j) {
        int col = wn * 64 + j * 16 + c;
        float bb = bias[n0 + col];
        #pragma unroll
        for (int r = 0; r < 4; ++r)
          Vl[wm * 64 + i * 16 + 4 * g + r][col] = f2bf(acc[i][j][r] + bb);
      }
    __syncthreads();
    int b_ = m0 >> 11, s0b = m0 & 2047;
    #pragma unroll
    for (int it = 0; it < 8; ++it) {
      int id = tid + it * 256;
      int nl = id >> 4, chm = (id & 15) * 8;
      unsigned short o8[8];
      #pragma unroll
      for (int jj = 0; jj < 8; ++jj) o8[jj] = Vl[chm + jj][nl];
      *(uint4*)(Vtb + ((size_t)b_ * D + n0 + nl) * S + s0b + chm) = *(const uint4*)o8;
    }
  }
}

// --------------------------------------------------------------- O GEMM ----
// 64x64 tiles, grid (8, 64) = 512 blocks (2/CU).
__global__ __launch_bounds__(256) void proj_o_kernel(
    const unsigned short* __restrict__ Ctx, const unsigned short* __restrict__ Bt,
    const float* __restrict__ bo, float* __restrict__ out)
{
  __shared__ __align__(16) unsigned short At[64][72];
  __shared__ __align__(16) unsigned short Btile[64][72];

  int tid = threadIdx.x;
  int w = tid >> 6, l = tid & 63;
  int g = l >> 4, c = l & 15;
  int wm = w >> 1, wn = w & 1;
  int m0 = blockIdx.y * 64, n0 = blockIdx.x * 64;

  f32x4 acc[2][2];
  #pragma unroll
  for (int i = 0; i < 2; ++i)
    #pragma unroll
    for (int j = 0; j < 2; ++j) acc[i][j] = f32x4{0.f, 0.f, 0.f, 0.f};

  for (int k0 = 0; k0 < D; k0 += 64) {
    __syncthreads();
    #pragma unroll
    for (int cc = 0; cc < 2; ++cc) {
      int id = tid + cc * 256;
      int row = id >> 3, ch = (id & 7) * 8;
      *(bf16x8*)&At[row][ch]    = ldg8(Ctx + (size_t)(m0 + row) * D + k0 + ch);
      *(bf16x8*)&Btile[row][ch] = ldg8(Bt  + (size_t)(n0 + row) * D + k0 + ch);
    }
    __syncthreads();
    #pragma unroll
    for (int dc = 0; dc < 2; ++dc) {
      bf16x8 af[2], bv4[2];
      #pragma unroll
      for (int i = 0; i < 2; ++i)
        af[i] = *(const bf16x8*)&At[wm * 32 + i * 16 + c][dc * 32 + 8 * g];
      #pragma unroll
      for (int j = 0; j < 2; ++j)
        bv4[j] = *(const bf16x8*)&Btile[wn * 32 + j * 16 + c][dc * 32 + 8 * g];
      #pragma unroll
      for (int i = 0; i < 2; ++i)
        #pragma unroll
        for (int j = 0; j < 2; ++j)
          acc[i][j] = mfma16(af[i], bv4[j], acc[i][j]);
    }
  }

  #pragma unroll
  for (int i = 0; i < 2; ++i)
    #pragma unroll
    for (int j = 0; j < 2; ++j) {
      int col = n0 + wn * 32 + j * 16 + c;
      float bb = bo[col];
      #pragma unroll
      for (int r = 0; r < 4; ++r) {
        int m = m0 + wm * 32 + i * 16 + 4 * g + r;
        out[(size_t)m * D + col] = acc[i][j][r] + bb;
      }
    }
}

// ----------------------------------------------------------- attention ----
// Swapped-QK^T 32x32 structure. grid(16 qblocks of 128, 16 bh), 256 thr =
// 4 waves x 32 q-rows. Lane owns one q-row (q = q0 + (l&31)); softmax is
// lane-local + one shfl_xor(32). P reaches PV B-frags via register shuffles.
// O accumulated transposed (mfma(V^T, P^T)) so rescale is lane-uniform.
__global__ __launch_bounds__(256) void attn_kernel(
    const unsigned short* __restrict__ Qb, const unsigned short* __restrict__ Kb,
    const unsigned short* __restrict__ Vtb, const float* __restrict__ mask,
    unsigned short* __restrict__ Ctx)
{
  __shared__ __align__(16) unsigned short Kt[64 * 64];   // [s][d] rows 128B, XOR swizzled
  __shared__ __align__(16) unsigned short Vt[64 * 64];   // [d][s] rows 128B, XOR swizzled
  __shared__ __align__(16) unsigned short Ol[4][32][72];

  int tid = threadIdx.x;
  int wid = tid >> 6, l = tid & 63;
  int ql = l & 31, half = l >> 5;
  int bh = blockIdx.y, b = bh >> 3, h = bh & 7;
  int q0 = blockIdx.x * 128 + wid * 32;
  int q = q0 + ql;

  // Q B-frags (Qb pre-scaled by 0.125*log2e): col=q, k = t*16 + half*8 + j.
  bf16x8 qf[4];
  #pragma unroll
  for (int t = 0; t < 4; ++t)
    qf[t] = ldg8(Qb + (size_t)(b * S + q) * D + h * DK + t * 16 + half * 8);

  float m_run = -1e30f, l_run = 0.f;
  f32x16 o0, o1;
  #pragma unroll
  for (int i = 0; i < 16; ++i) { o0[i] = 0.f; o1[i] = 0.f; }

  for (int kb = 0; kb < S; kb += 64) {
    __syncthreads();
    // stage K[64 s][64 d] and V^T[64 d][64 s] with XOR swizzle.
    #pragma unroll
    for (int it = 0; it < 2; ++it) {
      int id = tid + it * 256;
      int row = id >> 3, ch = id & 7;
      int sw = ((ch * 16) ^ ((row & 7) << 4)) >> 1;      // short offset in row
      *(bf16x8*)(Kt + row * 64 + sw) =
          ldg8(Kb + (size_t)(b * S + kb + row) * D + h * DK + ch * 8);
      *(bf16x8*)(Vt + row * 64 + sw) =
          ldg8(Vtb + ((size_t)b * D + h * DK + row) * S + kb + ch * 8);
    }
    __syncthreads();

    // S^T = K * Q^T : rows k (2 subtiles of 32), col q = ql.
    f32x16 s0, s1;
    #pragma unroll
    for (int i = 0; i < 16; ++i) { s0[i] = 0.f; s1[i] = 0.f; }
    #pragma unroll
    for (int t = 0; t < 4; ++t) {
      int cb = ((t * 32 + half * 16) ^ ((ql & 7) << 4)) >> 1;
      bf16x8 k0 = *(const bf16x8*)(Kt + ql * 64 + cb);
      bf16x8 k1 = *(const bf16x8*)(Kt + (32 + ql) * 64 + cb);
      s0 = mfma32(k0, qf[t], s0);
      s1 = mfma32(k1, qf[t], s1);
    }

    // mask (float4 runs) + lane-local masked scores y (log2 domain).
    float y[2][16];
    const float* mrow = mask + ((size_t)b * S + q) * S + kb;
    #pragma unroll
    for (int ks = 0; ks < 2; ++ks)
      #pragma unroll
      for (int rg = 0; rg < 4; ++rg) {
        float4 mv = *(const float4*)(mrow + ks * 32 + rg * 8 + half * 4);
        float sv0 = ks ? s1[rg * 4 + 0] : s0[rg * 4 + 0];
        float sv1 = ks ? s1[rg * 4 + 1] : s0[rg * 4 + 1];
        float sv2 = ks ? s1[rg * 4 + 2] : s0[rg * 4 + 2];
        float sv3 = ks ? s1[rg * 4 + 3] : s0[rg * 4 + 3];
        y[ks][rg * 4 + 0] = fmaf(sv0, mv.x, fmaf(EPS2, mv.x, -EPS2));
        y[ks][rg * 4 + 1] = fmaf(sv1, mv.y, fmaf(EPS2, mv.y, -EPS2));
        y[ks][rg * 4 + 2] = fmaf(sv2, mv.z, fmaf(EPS2, mv.z, -EPS2));
        y[ks][rg * 4 + 3] = fmaf(sv3, mv.w, fmaf(EPS2, mv.w, -EPS2));
      }

    // online softmax, lane-local + one cross-half exchange.
    float mx = -1e30f;
    #pragma unroll
    for (int ks = 0; ks < 2; ++ks)
      #pragma unroll
      for (int i = 0; i < 16; ++i) mx = fmaxf(mx, y[ks][i]);
    mx = fmaxf(mx, __shfl_xor(mx, 32, 64));
    float mnew = fmaxf(m_run, mx);
    float corr = exp2f(m_run - mnew);
    m_run = mnew;

    float p[2][16];
    float rs = 0.f;
    #pragma unroll
    for (int ks = 0; ks < 2; ++ks)
      #pragma unroll
      for (int i = 0; i < 16; ++i) {
        float pe = exp2f(y[ks][i] - mnew);
        p[ks][i] = pe;
        rs += pe;
      }
    rs += __shfl_xor(rs, 32, 64);
    l_run = l_run * corr + rs;
    o0 = o0 * corr;
    o1 = o1 * corr;

    // pack P to bf16 words and exchange across halves.
    unsigned w[2][4][2], xw[2][4][2];
    #pragma unroll
    for (int ks = 0; ks < 2; ++ks)
      #pragma unroll
      for (int rg = 0; rg < 4; ++rg) {
        w[ks][rg][0] = pk2(p[ks][rg * 4 + 0], p[ks][rg * 4 + 1]);
        w[ks][rg][1] = pk2(p[ks][rg * 4 + 2], p[ks][rg * 4 + 3]);
      }
    #pragma unroll
    for (int ks = 0; ks < 2; ++ks)
      #pragma unroll
      for (int rg = 0; rg < 4; ++rg) {
        xw[ks][rg][0] = (unsigned)__shfl_xor((int)w[ks][rg][0], 32, 64);
        xw[ks][rg][1] = (unsigned)__shfl_xor((int)w[ks][rg][1], 32, 64);
      }

    // assemble P^T B-frags: pa[kappa], k = kappa*16 + half*8 + j.
    bf16x8 pa[4];
    #pragma unroll
    for (int ks = 0; ks < 2; ++ks)
      #pragma unroll
      for (int sub = 0; sub < 2; ++sub) {
        unsigned u0 = half ? xw[ks][2 * sub + 1][0] : w[ks][2 * sub][0];
        unsigned u1 = half ? xw[ks][2 * sub + 1][1] : w[ks][2 * sub][1];
        unsigned u2 = half ? w[ks][2 * sub + 1][0]  : xw[ks][2 * sub][0];
        unsigned u3 = half ? w[ks][2 * sub + 1][1]  : xw[ks][2 * sub][1];
        union { unsigned u[4]; bf16x8 v; } pu;
        pu.u[0] = u0; pu.u[1] = u1; pu.u[2] = u2; pu.u[3] = u3;
        pa[ks * 2 + sub] = pu.v;
      }

    // O^T += V^T * P^T : o0 rows d 0..31, o1 rows d 32..63, col q = ql.
    #pragma unroll
    for (int kp = 0; kp < 4; ++kp) {
      int cb = ((kp * 32 + half * 16) ^ ((ql & 7) << 4)) >> 1;
      bf16x8 v0 = *(const bf16x8*)(Vt + ql * 64 + cb);
      bf16x8 v1 = *(const bf16x8*)(Vt + (32 + ql) * 64 + cb);
      o0 = mfma32(v0, pa[kp], o0);
      o1 = mfma32(v1, pa[kp], o1);
    }
  }

  // epilogue: normalize, transpose via per-wave LDS, write coalesced.
  float inv = 1.0f / l_run;
  #pragma unroll
  for (int i = 0; i < 16; ++i) {
    int dr = (i & 3) + 8 * (i >> 2) + 4 * half;
    Ol[wid][ql][dr]      = f2bf(o0[i] * inv);
    Ol[wid][ql][32 + dr] = f2bf(o1[i] * inv);
  }
  // same-wave LDS write->read (no barrier needed; in-order DS pipe, idiom
  // validated by R3's Pl round-trip).
  #pragma unroll
  for (int it = 0; it < 4; ++it) {
    int id = l + it * 64;
    int row = id >> 3, ch = (id & 7) * 8;
    bf16x8 vv = *(const bf16x8*)&Ol[wid][row][ch];
    *(bf16x8*)(Ctx + (size_t)(b * S + q0 + row) * D + h * DK + ch) = vv;
  }
}

// ------------------------------------------------------------- launcher ----
extern "C" void kernel_launch(void* const* d_in, const int* in_sizes, int n_in,
                              void* d_out, int out_size, void* d_ws, size_t ws_size,
                              hipStream_t stream) {
  (void)in_sizes; (void)n_in; (void)out_size; (void)ws_size;
  const float* query = (const float*)d_in[0];
  const float* key   = (const float*)d_in[1];
  const float* value = (const float*)d_in[2];
  const float* mask  = (const float*)d_in[3];
  const float* Wq    = (const float*)d_in[4];
  const float* bq    = (const float*)d_in[5];
  const float* Wk    = (const float*)d_in[6];
  const float* bk    = (const float*)d_in[7];
  const float* Wv    = (const float*)d_in[8];
  const float* bv    = (const float*)d_in[9];
  const float* Wo    = (const float*)d_in[10];
  const float* bo    = (const float*)d_in[11];
  float* out = (float*)d_out;

  char* ws = (char*)d_ws;
  unsigned short* Wt  = (unsigned short*)(ws);                 //  2 MB
  unsigned short* Qb  = (unsigned short*)(ws + 2097152);       //  4 MB
  unsigned short* Kb  = (unsigned short*)(ws + 6291456);       //  4 MB
  unsigned short* Vtb = (unsigned short*)(ws + 10485760);      //  4 MB
  unsigned short* Ctx = (unsigned short*)(ws + 14680064);      //  4 MB (18 MB total)

  hipLaunchKernelGGL(prep_w_kernel, dim3(256), dim3(256), 0, stream,
                     Wq, Wk, Wv, Wo, Wt);
  hipLaunchKernelGGL(proj_qkv_kernel, dim3(4, 32, 3), dim3(256), 0, stream,
                     query, key, value, Wt, bq, bk, bv, Qb, Kb, Vtb);
  hipLaunchKernelGGL(attn_kernel, dim3(16, 16), dim3(256), 0, stream,
                     Qb, Kb, Vtb, mask, Ctx);
  hipLaunchKernelGGL(proj_o_kernel, dim3(8, 64), dim3(256), 0, stream,
                     Ctx, Wt + 3 * D * D, bo, out);
}

// Round 10
// 213.363 us; speedup vs baseline: 1.0915x; 1.0915x over previous
//
#include <hip/hip_runtime.h>
#include <hip/hip_bf16.h>

// MultiHeadedAttention fused pipeline for MI355X (gfx950), bf16 MFMA path.
// R10 = R9/R8/R7/R6 re-audited, unchanged structure (never ran: acq timeouts).
// attn: swapped-QK^T 32x32 MFMA, KV-split (adaptive 4/2/1 on ws_size) for 4x
// TLP (R5 measured 1 wave/SIMD latency-bound: Occ 10.5%, MfmaUtil 6%),
// register-prefetched K/V staging (T14), LSE merge kernel.

#define DEVI __device__ __forceinline__

typedef float f32x4 __attribute__((ext_vector_type(4)));
typedef float f32x16 __attribute__((ext_vector_type(16)));
typedef __bf16 bf16x8 __attribute__((ext_vector_type(8)));

constexpr int S  = 2048;
constexpr int D  = 512;
constexpr int H  = 8;
constexpr int DK = 64;
constexpr int BATCH = 2;
constexpr int BS = BATCH * S;  // 4096

constexpr float SCALE_QK = 0.18033688011112433f;  // 0.125 * log2(e)
constexpr float EPS2     = 1.4426950408889634e9f; // 1e9 * log2(e)

DEVI unsigned short f2bf(float f) {
  union { float f; unsigned u; } v; v.f = f;
  unsigned r = v.u + 0x7fffu + ((v.u >> 16) & 1u);  // round-to-nearest-even
  return (unsigned short)(r >> 16);
}

DEVI unsigned pk2(float a, float b) {
  return (unsigned)f2bf(a) | ((unsigned)f2bf(b) << 16);
}

DEVI f32x4 mfma16(bf16x8 a, bf16x8 b, f32x4 c) {
  return __builtin_amdgcn_mfma_f32_16x16x32_bf16(a, b, c, 0, 0, 0);
}
DEVI f32x16 mfma32(bf16x8 a, bf16x8 b, f32x16 c) {
  return __builtin_amdgcn_mfma_f32_32x32x16_bf16(a, b, c, 0, 0, 0);
}

DEVI bf16x8 ldg8(const unsigned short* p) { return *(const bf16x8*)p; }
DEVI float bf2f(unsigned short u) {
  union { unsigned u; float f; } v; v.u = (unsigned)u << 16; return v.f;
}

// -------------------------------------------------------------- prep_w ----
__global__ __launch_bounds__(256) void prep_w_kernel(
    const float* __restrict__ Wq, const float* __restrict__ Wk,
    const float* __restrict__ Wv, const float* __restrict__ Wo,
    unsigned short* __restrict__ Wt)
{
  __shared__ float T[64][65];
  int bid = blockIdx.x;
  int g = bid >> 6, t = bid & 63;
  int tn = t >> 3, td = t & 7;
  int n0 = tn * 64, d0 = td * 64;
  int tid = threadIdx.x;
  const float* src = (g == 0) ? Wq : (g == 1) ? Wk : (g == 2) ? Wv : Wo;

  #pragma unroll
  for (int cc = 0; cc < 4; ++cc) {
    int id = tid + cc * 256;
    int dd = id >> 4, f4 = (id & 15) * 4;
    const float* p = (g < 3)
      ? src + ((size_t)tn * D + d0 + dd) * DK + f4
      : src + (size_t)(d0 + dd) * D + n0 + f4;
    float4 x = *(const float4*)p;
    T[dd][f4 + 0] = x.x; T[dd][f4 + 1] = x.y;
    T[dd][f4 + 2] = x.z; T[dd][f4 + 3] = x.w;
  }
  __syncthreads();

  #pragma unroll
  for (int cc = 0; cc < 2; ++cc) {
    int id = tid + cc * 256;
    int nn = id >> 3, ch = (id & 7) * 8;
    unsigned short o8[8];
    #pragma unroll
    for (int j = 0; j < 8; ++j) o8[j] = f2bf(T[ch + j][nn]);
    *(uint4*)&Wt[((size_t)g * D + n0 + nn) * D + d0 + ch] = *(const uint4*)o8;
  }
}

// ------------------------------------------------------------- QKV GEMM ----
__global__ __launch_bounds__(256) void proj_qkv_kernel(
    const float* __restrict__ query, const float* __restrict__ key,
    const float* __restrict__ value, const unsigned short* __restrict__ Wt,
    const float* __restrict__ bq, const float* __restrict__ bk, const float* __restrict__ bv,
    unsigned short* __restrict__ Qb, unsigned short* __restrict__ Kb,
    unsigned short* __restrict__ Vtb)
{
  int z = blockIdx.z;
  const float* A = (z == 0) ? query : (z == 1) ? key : value;
  const unsigned short* Bt = Wt + (size_t)z * D * D;
  const float* bias = (z == 0) ? bq : (z == 1) ? bk : bv;

  __shared__ __align__(16) unsigned short SM[2 * 128 * 72];
  unsigned short (*At)[72]    = (unsigned short(*)[72])SM;
  unsigned short (*Btile)[72] = (unsigned short(*)[72])(SM + 128 * 72);

  int tid = threadIdx.x;
  int w = tid >> 6, l = tid & 63;
  int g = l >> 4, c = l & 15;
  int wm = w >> 1, wn = w & 1;
  int m0 = blockIdx.y * 128, n0 = blockIdx.x * 128;

  f32x4 acc[4][4];
  #pragma unroll
  for (int i = 0; i < 4; ++i)
    #pragma unroll
    for (int j = 0; j < 4; ++j) acc[i][j] = f32x4{0.f, 0.f, 0.f, 0.f};

  for (int k0 = 0; k0 < D; k0 += 64) {
    __syncthreads();
    #pragma unroll
    for (int cc = 0; cc < 4; ++cc) {
      int id = tid + cc * 256;
      int row = id >> 3, ch = (id & 7) * 8;
      const float* p = A + (size_t)(m0 + row) * D + k0 + ch;
      float4 x0 = *(const float4*)p, x1 = *(const float4*)(p + 4);
      unsigned short o8[8] = { f2bf(x0.x), f2bf(x0.y), f2bf(x0.z), f2bf(x0.w),
                               f2bf(x1.x), f2bf(x1.y), f2bf(x1.z), f2bf(x1.w) };
      *(uint4*)&At[row][ch] = *(const uint4*)o8;
      *(bf16x8*)&Btile[row][ch] = ldg8(Bt + (size_t)(n0 + row) * D + k0 + ch);
    }
    __syncthreads();
    #pragma unroll
    for (int dc = 0; dc < 2; ++dc) {
      bf16x8 af[4], bv4[4];
      #pragma unroll
      for (int i = 0; i < 4; ++i)
        af[i] = *(const bf16x8*)&At[wm * 64 + i * 16 + c][dc * 32 + 8 * g];
      #pragma unroll
      for (int j = 0; j < 4; ++j)
        bv4[j] = *(const bf16x8*)&Btile[wn * 64 + j * 16 + c][dc * 32 + 8 * g];
      #pragma unroll
      for (int i = 0; i < 4; ++i)
        #pragma unroll
        for (int j = 0; j < 4; ++j)
          acc[i][j] = mfma16(af[i], bv4[j], acc[i][j]);
    }
  }

  if (z < 2) {
    #pragma unroll
    for (int i = 0; i < 4; ++i) {
      #pragma unroll
      for (int j = 0; j < 4; ++j) {
        int col = n0 + wn * 64 + j * 16 + c;
        float bb = bias[col];
        #pragma unroll
        for (int r = 0; r < 4; ++r) {
          int m = m0 + wm * 64 + i * 16 + 4 * g + r;
          float vv = acc[i][j][r] + bb;
          if (z == 0) vv *= SCALE_QK;
          unsigned short o = f2bf(vv);
          if (z == 0) Qb[(size_t)m * D + col] = o;
          else        Kb[(size_t)m * D + col] = o;
        }
      }
    }
  } else {
    __syncthreads();
    unsigned short (*Vl)[130] = (unsigned short(*)[130])SM;
    #pragma unroll
    for (int i = 0; i < 4; ++i)
      #pragma unroll
      for (int j = 0; j < 4; ++j) {
        int col = wn * 64 + j * 16 + c;
        float bb = bias[n0 + col];
        #pragma unroll
        for (int r = 0; r < 4; ++r)
          Vl[wm * 64 + i * 16 + 4 * g + r][col] = f2bf(acc[i][j][r] + bb);
      }
    __syncthreads();
    int b_ = m0 >> 11, s0b = m0 & 2047;
    #pragma unroll
    for (int it = 0; it < 8; ++it) {
      int id = tid + it * 256;
      int nl = id >> 4, chm = (id & 15) * 8;
      unsigned short o8[8];
      #pragma unroll
      for (int jj = 0; jj < 8; ++jj) o8[jj] = Vl[chm + jj][nl];
      *(uint4*)(Vtb + ((size_t)b_ * D + n0 + nl) * S + s0b + chm) = *(const uint4*)o8;
    }
  }
}

// --------------------------------------------------------------- O GEMM ----
__global__ __launch_bounds__(256) void proj_o_kernel(
    const unsigned short* __restrict__ Ctx, const unsigned short* __restrict__ Bt,
    const float* __restrict__ bo, float* __restrict__ out)
{
  __shared__ __align__(16) unsigned short At[64][72];
  __shared__ __align__(16) unsigned short Btile[64][72];

  int tid = threadIdx.x;
  int w = tid >> 6, l = tid & 63;
  int g = l >> 4, c = l & 15;
  int wm = w >> 1, wn = w & 1;
  int m0 = blockIdx.y * 64, n0 = blockIdx.x * 64;

  f32x4 acc[2][2];
  #pragma unroll
  for (int i = 0; i < 2; ++i)
    #pragma unroll
    for (int j = 0; j < 2; ++j) acc[i][j] = f32x4{0.f, 0.f, 0.f, 0.f};

  for (int k0 = 0; k0 < D; k0 += 64) {
    __syncthreads();
    #pragma unroll
    for (int cc = 0; cc < 2; ++cc) {
      int id = tid + cc * 256;
      int row = id >> 3, ch = (id & 7) * 8;
      *(bf16x8*)&At[row][ch]    = ldg8(Ctx + (size_t)(m0 + row) * D + k0 + ch);
      *(bf16x8*)&Btile[row][ch] = ldg8(Bt  + (size_t)(n0 + row) * D + k0 + ch);
    }
    __syncthreads();
    #pragma unroll
    for (int dc = 0; dc < 2; ++dc) {
      bf16x8 af[2], bv4[2];
      #pragma unroll
      for (int i = 0; i < 2; ++i)
        af[i] = *(const bf16x8*)&At[wm * 32 + i * 16 + c][dc * 32 + 8 * g];
      #pragma unroll
      for (int j = 0; j < 2; ++j)
        bv4[j] = *(const bf16x8*)&Btile[wn * 32 + j * 16 + c][dc * 32 + 8 * g];
      #pragma unroll
      for (int i = 0; i < 2; ++i)
        #pragma unroll
        for (int j = 0; j < 2; ++j)
          acc[i][j] = mfma16(af[i], bv4[j], acc[i][j]);
    }
  }

  #pragma unroll
  for (int i = 0; i < 2; ++i)
    #pragma unroll
    for (int j = 0; j < 2; ++j) {
      int col = n0 + wn * 32 + j * 16 + c;
      float bb = bo[col];
      #pragma unroll
      for (int r = 0; r < 4; ++r) {
        int m = m0 + wm * 32 + i * 16 + 4 * g + r;
        out[(size_t)m * D + col] = acc[i][j][r] + bb;
      }
    }
}

// ----------------------------------------------------------- attention ----
// Swapped-QK^T 32x32, KV-split. grid(16 qblocks, 16 bh, nsplit), 256 thr =
// 4 waves x 32 q-rows. Each split covers kvlen columns; emits unnormalized
// partial O (bf16) + m/l (fp32, log2 domain) unless direct==1.
// K/V staging register-prefetched one tile ahead (T14).
__global__ __launch_bounds__(256, 4) void attn_kernel(
    const unsigned short* __restrict__ Qb, const unsigned short* __restrict__ Kb,
    const unsigned short* __restrict__ Vtb, const float* __restrict__ mask,
    unsigned short* __restrict__ Ctx, unsigned short* __restrict__ Opart,
    float* __restrict__ Mpart, float* __restrict__ Lpart,
    int kvlen, int direct)
{
  __shared__ __align__(16) unsigned short Kt[64 * 64];   // XOR swizzled
  __shared__ __align__(16) unsigned short Vt[64 * 64];   // XOR swizzled
  __shared__ __align__(16) unsigned short Ol[4][32][72];

  int tid = threadIdx.x;
  int wid = tid >> 6, l = tid & 63;
  int ql = l & 31, half = l >> 5;
  int bh = blockIdx.y, b = bh >> 3, h = bh & 7;
  int sp = blockIdx.z;
  int kv0 = sp * kvlen;
  int ntiles = kvlen >> 6;
  int q0 = blockIdx.x * 128 + wid * 32;
  int q = q0 + ql;

  bf16x8 qf[4];
  #pragma unroll
  for (int t = 0; t < 4; ++t)
    qf[t] = ldg8(Qb + (size_t)(b * S + q) * D + h * DK + t * 16 + half * 8);

  float m_run = -1e30f, l_run = 0.f;
  f32x16 o0, o1;
  #pragma unroll
  for (int i = 0; i < 16; ++i) { o0[i] = 0.f; o1[i] = 0.f; }

  // staging prefetch registers
  int srow = tid >> 3, sch = tid & 7;
  int ssw = ((sch * 16) ^ ((srow & 7) << 4)) >> 1;
  int srow2 = (tid + 256) >> 3, sch2 = (tid + 256) & 7;
  int ssw2 = ((sch2 * 16) ^ ((srow2 & 7) << 4)) >> 1;
  bf16x8 kpre0, kpre1, vpre0, vpre1;
  {
    kpre0 = ldg8(Kb + (size_t)(b * S + kv0 + srow) * D + h * DK + sch * 8);
    vpre0 = ldg8(Vtb + ((size_t)b * D + h * DK + srow) * S + kv0 + sch * 8);
    kpre1 = ldg8(Kb + (size_t)(b * S + kv0 + srow2) * D + h * DK + sch2 * 8);
    vpre1 = ldg8(Vtb + ((size_t)b * D + h * DK + srow2) * S + kv0 + sch2 * 8);
  }

  for (int t = 0; t < ntiles; ++t) {
    int kb = kv0 + t * 64;
    __syncthreads();
    *(bf16x8*)(Kt + srow * 64 + ssw)   = kpre0;
    *(bf16x8*)(Vt + srow * 64 + ssw)   = vpre0;
    *(bf16x8*)(Kt + srow2 * 64 + ssw2) = kpre1;
    *(bf16x8*)(Vt + srow2 * 64 + ssw2) = vpre1;
    if (t + 1 < ntiles) {
      int kn = kb + 64;
      kpre0 = ldg8(Kb + (size_t)(b * S + kn + srow) * D + h * DK + sch * 8);
      vpre0 = ldg8(Vtb + ((size_t)b * D + h * DK + srow) * S + kn + sch * 8);
      kpre1 = ldg8(Kb + (size_t)(b * S + kn + srow2) * D + h * DK + sch2 * 8);
      vpre1 = ldg8(Vtb + ((size_t)b * D + h * DK + srow2) * S + kn + sch2 * 8);
    }
    __syncthreads();

    // S^T = K * Q^T : rows k (2 subtiles of 32), col q = ql.
    f32x16 s0, s1;
    #pragma unroll
    for (int i = 0; i < 16; ++i) { s0[i] = 0.f; s1[i] = 0.f; }
    #pragma unroll
    for (int t4 = 0; t4 < 4; ++t4) {
      int cb = ((t4 * 32 + half * 16) ^ ((ql & 7) << 4)) >> 1;
      bf16x8 k0 = *(const bf16x8*)(Kt + ql * 64 + cb);
      bf16x8 k1 = *(const bf16x8*)(Kt + (32 + ql) * 64 + cb);
      s0 = mfma32(k0, qf[t4], s0);
      s1 = mfma32(k1, qf[t4], s1);
    }

    // mask + lane-local masked scores y (log2 domain).
    float y[2][16];
    const float* mrow = mask + ((size_t)b * S + q) * S + kb;
    #pragma unroll
    for (int ks = 0; ks < 2; ++ks)
      #pragma unroll
      for (int rg = 0; rg < 4; ++rg) {
        float4 mv = *(const float4*)(mrow + ks * 32 + rg * 8 + half * 4);
        float sv0 = ks ? s1[rg * 4 + 0] : s0[rg * 4 + 0];
        float sv1 = ks ? s1[rg * 4 + 1] : s0[rg * 4 + 1];
        float sv2 = ks ? s1[rg * 4 + 2] : s0[rg * 4 + 2];
        float sv3 = ks ? s1[rg * 4 + 3] : s0[rg * 4 + 3];
        y[ks][rg * 4 + 0] = fmaf(sv0, mv.x, fmaf(EPS2, mv.x, -EPS2));
        y[ks][rg * 4 + 1] = fmaf(sv1, mv.y, fmaf(EPS2, mv.y, -EPS2));
        y[ks][rg * 4 + 2] = fmaf(sv2, mv.z, fmaf(EPS2, mv.z, -EPS2));
        y[ks][rg * 4 + 3] = fmaf(sv3, mv.w, fmaf(EPS2, mv.w, -EPS2));
      }

    // online softmax, lane-local + one cross-half exchange.
    float mx = -1e30f;
    #pragma unroll
    for (int ks = 0; ks < 2; ++ks)
      #pragma unroll
      for (int i = 0; i < 16; ++i) mx = fmaxf(mx, y[ks][i]);
    mx = fmaxf(mx, __shfl_xor(mx, 32, 64));
    float mnew = fmaxf(m_run, mx);
    float corr = exp2f(m_run - mnew);
    m_run = mnew;

    float p[2][16];
    float rs = 0.f;
    #pragma unroll
    for (int ks = 0; ks < 2; ++ks)
      #pragma unroll
      for (int i = 0; i < 16; ++i) {
        float pe = exp2f(y[ks][i] - mnew);
        p[ks][i] = pe;
        rs += pe;
      }
    rs += __shfl_xor(rs, 32, 64);
    l_run = l_run * corr + rs;
    o0 = o0 * corr;
    o1 = o1 * corr;

    // pack P to bf16 words and exchange across halves.
    unsigned w[2][4][2], xw[2][4][2];
    #pragma unroll
    for (int ks = 0; ks < 2; ++ks)
      #pragma unroll
      for (int rg = 0; rg < 4; ++rg) {
        w[ks][rg][0] = pk2(p[ks][rg * 4 + 0], p[ks][rg * 4 + 1]);
        w[ks][rg][1] = pk2(p[ks][rg * 4 + 2], p[ks][rg * 4 + 3]);
      }
    #pragma unroll
    for (int ks = 0; ks < 2; ++ks)
      #pragma unroll
      for (int rg = 0; rg < 4; ++rg) {
        xw[ks][rg][0] = (unsigned)__shfl_xor((int)w[ks][rg][0], 32, 64);
        xw[ks][rg][1] = (unsigned)__shfl_xor((int)w[ks][rg][1], 32, 64);
      }

    bf16x8 pa[4];
    #pragma unroll
    for (int ks = 0; ks < 2; ++ks)
      #pragma unroll
      for (int sub = 0; sub < 2; ++sub) {
        unsigned u0 = half ? xw[ks][2 * sub + 1][0] : w[ks][2 * sub][0];
        unsigned u1 = half ? xw[ks][2 * sub + 1][1] : w[ks][2 * sub][1];
        unsigned u2 = half ? w[ks][2 * sub + 1][0]  : xw[ks][2 * sub][0];
        unsigned u3 = half ? w[ks][2 * sub + 1][1]  : xw[ks][2 * sub][1];
        union { unsigned u[4]; bf16x8 v; } pu;
        pu.u[0] = u0; pu.u[1] = u1; pu.u[2] = u2; pu.u[3] = u3;
        pa[ks * 2 + sub] = pu.v;
      }

    // O^T += V^T * P^T
    #pragma unroll
    for (int kp = 0; kp < 4; ++kp) {
      int cb = ((kp * 32 + half * 16) ^ ((ql & 7) << 4)) >> 1;
      bf16x8 v0 = *(const bf16x8*)(Vt + ql * 64 + cb);
      bf16x8 v1 = *(const bf16x8*)(Vt + (32 + ql) * 64 + cb);
      o0 = mfma32(v0, pa[kp], o0);
      o1 = mfma32(v1, pa[kp], o1);
    }
  }

  // epilogue: transpose via per-wave LDS (bf16), then either direct
  // normalized Ctx write (nsplit==1) or unnormalized partial write.
  float sc = direct ? (1.0f / l_run) : 1.0f;
  #pragma unroll
  for (int i = 0; i < 16; ++i) {
    int dr = (i & 3) + 8 * (i >> 2) + 4 * half;
    Ol[wid][ql][dr]      = f2bf(o0[i] * sc);
    Ol[wid][ql][32 + dr] = f2bf(o1[i] * sc);
  }
  if (!direct && half == 0) {
    size_t mi = ((size_t)sp * 16 + bh) * 2048 + q;
    Mpart[mi] = m_run;
    Lpart[mi] = l_run;
  }
  // same-wave LDS write->read (no barrier; in-order DS pipe, R3-validated).
  #pragma unroll
  for (int it = 0; it < 4; ++it) {
    int id = l + it * 64;
    int row = id >> 3, ch = (id & 7) * 8;
    bf16x8 vv = *(const bf16x8*)&Ol[wid][row][ch];
    if (direct)
      *(bf16x8*)(Ctx + (size_t)(b * S + q0 + row) * D + h * DK + ch) = vv;
    else
      *(bf16x8*)(Opart + (((size_t)sp * 16 + bh) * 2048 + q0 + row) * DK + ch) = vv;
  }
}

// ------------------------------------------------------- attn merge ----
// Combine NSPLIT partials: O = sum_sp w_sp*O_sp / sum_sp w_sp*l_sp,
// w_sp = exp2(m_sp - M). grid 1024x256 = 16bh * 2048q * 8chunks.
template <int NSPLIT>
__global__ __launch_bounds__(256) void attn_merge_kernel(
    const unsigned short* __restrict__ Opart, const float* __restrict__ Mpart,
    const float* __restrict__ Lpart, unsigned short* __restrict__ Ctx)
{
  int tid = blockIdx.x * 256 + threadIdx.x;
  int chunk = tid & 7;
  int q = (tid >> 3) & 2047;
  int bh = tid >> 14;
  int b = bh >> 3, h = bh & 7;

  float ms[NSPLIT], ls[NSPLIT];
  float M = -3e38f;
  #pragma unroll
  for (int sp = 0; sp < NSPLIT; ++sp) {
    size_t mi = ((size_t)sp * 16 + bh) * 2048 + q;
    ms[sp] = Mpart[mi];
    ls[sp] = Lpart[mi];
    M = fmaxf(M, ms[sp]);
  }
  float osum[8];
  #pragma unroll
  for (int j = 0; j < 8; ++j) osum[j] = 0.f;
  float lsum = 0.f;
  #pragma unroll
  for (int sp = 0; sp < NSPLIT; ++sp) {
    float wsp = exp2f(ms[sp] - M);
    lsum += wsp * ls[sp];
    bf16x8 ov = ldg8(Opart + (((size_t)sp * 16 + bh) * 2048 + q) * DK + chunk * 8);
    #pragma unroll
    for (int j = 0; j < 8; ++j) osum[j] += wsp * bf2f(((unsigned short*)&ov)[j]);
  }
  float inv = 1.0f / lsum;
  unsigned short o8[8];
  #pragma unroll
  for (int j = 0; j < 8; ++j) o8[j] = f2bf(osum[j] * inv);
  *(uint4*)(Ctx + (size_t)(b * S + q) * D + h * DK + chunk * 8) = *(const uint4*)o8;
}

// ------------------------------------------------------------- launcher ----
extern "C" void kernel_launch(void* const* d_in, const int* in_sizes, int n_in,
                              void* d_out, int out_size, void* d_ws, size_t ws_size,
                              hipStream_t stream) {
  (void)in_sizes; (void)n_in; (void)out_size;
  const float* query = (const float*)d_in[0];
  const float* key   = (const float*)d_in[1];
  const float* value = (const float*)d_in[2];
  const float* mask  = (const float*)d_in[3];
  const float* Wq    = (const float*)d_in[4];
  const float* bq    = (const float*)d_in[5];
  const float* Wk    = (const float*)d_in[6];
  const float* bk    = (const float*)d_in[7];
  const float* Wv    = (const float*)d_in[8];
  const float* bv    = (const float*)d_in[9];
  const float* Wo    = (const float*)d_in[10];
  const float* bo    = (const float*)d_in[11];
  float* out = (float*)d_out;

  char* ws = (char*)d_ws;
  unsigned short* Wt  = (unsigned short*)(ws);                 //  2 MB
  unsigned short* Qb  = (unsigned short*)(ws + 2097152);       //  4 MB
  unsigned short* Kb  = (unsigned short*)(ws + 6291456);       //  4 MB
  unsigned short* Vtb = (unsigned short*)(ws + 10485760);      //  4 MB
  unsigned short* Ctx = (unsigned short*)(ws + 14680064);      //  4 MB -> 18,874,368

  // adaptive KV-split on ws budget: per split 4 MB O (bf16) + 2*128 KB m/l.
  const size_t base = 18874368ull, per = 4456448ull;
  int nsplit = (ws_size >= base + 4 * per) ? 4
             : (ws_size >= base + 2 * per) ? 2 : 1;
  unsigned short* Opart = (unsigned short*)(ws + base);
  float* Mpart = (float*)(ws + base + (size_t)nsplit * 4194304);
  float* Lpart = (float*)(ws + base + (size_t)nsplit * 4194304 + (size_t)nsplit * 131072);
  int kvlen = S / nsplit;

  hipLaunchKernelGGL(prep_w_kernel, dim3(256), dim3(256), 0, stream,
                     Wq, Wk, Wv, Wo, Wt);
  hipLaunchKernelGGL(proj_qkv_kernel, dim3(4, 32, 3), dim3(256), 0, stream,
                     query, key, value, Wt, bq, bk, bv, Qb, Kb, Vtb);
  hipLaunchKernelGGL(attn_kernel, dim3(16, 16, nsplit), dim3(256), 0, stream,
                     Qb, Kb, Vtb, mask, Ctx, Opart, Mpart, Lpart,
                     kvlen, (int)(nsplit == 1));
  if (nsplit == 4)
    hipLaunchKernelGGL(attn_merge_kernel<4>, dim3(1024), dim3(256), 0, stream,
                       Opart, Mpart, Lpart, Ctx);
  else if (nsplit == 2)
    hipLaunchKernelGGL(attn_merge_kernel<2>, dim3(1024), dim3(256), 0, stream,
                       Opart, Mpart, Lpart, Ctx);
  hipLaunchKernelGGL(proj_o_kernel, dim3(8, 64), dim3(256), 0, stream,
                     Ctx, Wt + 3 * D * D, bo, out);
}